// Round 1
// baseline (6509.940 us; speedup 1.0000x reference)
//
#include <hip/hip_runtime.h>

#define N_USER 100000
#define N_ITEM 200000
#define N_NODES 300000
#define LATDIM 64
#define N_EDGE 9600000

// out = concat(u, i); cur = concat(u, i)   (vectorized float4)
__global__ void lgcn_init_kernel(const float* __restrict__ u,
                                 const float* __restrict__ it,
                                 float* __restrict__ out,
                                 float* __restrict__ cur) {
    const size_t total4 = (size_t)N_NODES * LATDIM / 4;
    const size_t u4 = (size_t)N_USER * LATDIM / 4;
    const float4* uu = (const float4*)u;
    const float4* ii = (const float4*)it;
    float4* o4 = (float4*)out;
    float4* c4 = (float4*)cur;
    for (size_t i = (size_t)blockIdx.x * blockDim.x + threadIdx.x; i < total4;
         i += (size_t)gridDim.x * blockDim.x) {
        float4 v = (i < u4) ? uu[i] : ii[i - u4];
        o4[i] = v;
        c4[i] = v;
    }
}

// One edge per 64-lane wave; lane = latent dim.
// nxt[row][lane] += val * cur[col][lane]
__global__ void lgcn_scatter_kernel(const int* __restrict__ row,
                                    const int* __restrict__ col,
                                    const float* __restrict__ vals,
                                    const float* __restrict__ cur,
                                    float* __restrict__ nxt) {
    const int wavesPerBlock = blockDim.x >> 6;
    int e = blockIdx.x * wavesPerBlock + (threadIdx.x >> 6);
    int lane = threadIdx.x & 63;
    if (e >= N_EDGE) return;
    int r = row[e];
    int c = col[e];
    float v = vals[e];
    float x = cur[(size_t)c * LATDIM + lane];
    atomicAdd(&nxt[(size_t)r * LATDIM + lane], v * x);
}

// out += src   (vectorized float4, grid-stride)
__global__ void lgcn_add_kernel(float* __restrict__ out,
                                const float* __restrict__ src) {
    const size_t total4 = (size_t)N_NODES * LATDIM / 4;
    float4* o4 = (float4*)out;
    const float4* s4 = (const float4*)src;
    for (size_t i = (size_t)blockIdx.x * blockDim.x + threadIdx.x; i < total4;
         i += (size_t)gridDim.x * blockDim.x) {
        float4 a = o4[i];
        float4 b = s4[i];
        a.x += b.x; a.y += b.y; a.z += b.z; a.w += b.w;
        o4[i] = a;
    }
}

extern "C" void kernel_launch(void* const* d_in, const int* in_sizes, int n_in,
                              void* d_out, int out_size, void* d_ws, size_t ws_size,
                              hipStream_t stream) {
    const float* uEmb = (const float*)d_in[0];
    const float* iEmb = (const float*)d_in[1];
    const int* erow = (const int*)d_in[2];
    const int* ecol = (const int*)d_in[3];
    const float* evals = (const float*)d_in[4];
    float* out = (float*)d_out;

    const size_t bufElems = (size_t)N_NODES * LATDIM;         // 19.2M floats
    const size_t bufBytes = bufElems * sizeof(float);         // 76.8 MB
    float* bufA = (float*)d_ws;
    float* bufB = (float*)((char*)d_ws + bufBytes);

    const int THREADS = 256;
    const int GRID_ELEM = 2048;  // grid-stride for elementwise kernels
    const int edgesPerBlock = THREADS / 64;                   // 4
    const int GRID_SCAT = (N_EDGE + edgesPerBlock - 1) / edgesPerBlock;

    // out = cur = concat(u, i)
    lgcn_init_kernel<<<GRID_ELEM, THREADS, 0, stream>>>(uEmb, iEmb, out, bufA);

    float* cur = bufA;
    float* nxt = bufB;
    for (int layer = 0; layer < 3; ++layer) {
        hipMemsetAsync(nxt, 0, bufBytes, stream);
        lgcn_scatter_kernel<<<GRID_SCAT, THREADS, 0, stream>>>(erow, ecol, evals,
                                                               cur, nxt);
        lgcn_add_kernel<<<GRID_ELEM, THREADS, 0, stream>>>(out, nxt);
        float* t = cur; cur = nxt; nxt = t;
    }
}

// Round 2
// 2664.913 us; speedup vs baseline: 2.4428x; 2.4428x over previous
//
#include <hip/hip_runtime.h>

#define N_USER 100000
#define N_ITEM 200000
#define N_NODES 300000
#define LATDIM 64
#define N_EDGE 9600000
#define NCHUNK ((N_NODES + 255) / 256)   // 1172

__device__ __forceinline__ unsigned int pack_bf16x2(float a, float b) {
    unsigned int ua = __float_as_uint(a);
    unsigned int ub = __float_as_uint(b);
    ua = (ua + 0x7fffu + ((ua >> 16) & 1u)) >> 16;   // RNE
    ub = (ub + 0x7fffu + ((ub >> 16) & 1u)) >> 16;
    return ua | (ub << 16);
}
__device__ __forceinline__ unsigned short f32_to_bf16(float a) {
    unsigned int ua = __float_as_uint(a);
    return (unsigned short)((ua + 0x7fffu + ((ua >> 16) & 1u)) >> 16);
}

// out = concat(u,i) fp32; curA = bf16x2-packed concat(u,i)
__global__ void lgcn_init(const float* __restrict__ u,
                          const float* __restrict__ it,
                          float* __restrict__ out,
                          unsigned int* __restrict__ curp) {
    const size_t total2 = (size_t)N_NODES * 32;   // float2 pairs
    const size_t u2 = (size_t)N_USER * 32;
    const float2* uu = (const float2*)u;
    const float2* ii = (const float2*)it;
    float2* o2 = (float2*)out;
    for (size_t i = (size_t)blockIdx.x * blockDim.x + threadIdx.x; i < total2;
         i += (size_t)gridDim.x * blockDim.x) {
        float2 v = (i < u2) ? uu[i] : ii[i - u2];
        o2[i] = v;
        curp[i] = pack_bf16x2(v.x, v.y);
    }
}

// histogram of rows into cnt[]
__global__ void lgcn_hist(const int* __restrict__ row, int* __restrict__ cnt) {
    int e = blockIdx.x * blockDim.x + threadIdx.x;
    if (e < N_EDGE) atomicAdd(&cnt[row[e]], 1);
}

// per-chunk (256 elems) sums of cnt -> chunkSum
__global__ void lgcn_chunksum(const int* __restrict__ cnt, int* __restrict__ chunkSum) {
    __shared__ int s[256];
    int tid = threadIdx.x;
    int i = blockIdx.x * 256 + tid;
    s[tid] = (i < N_NODES) ? cnt[i] : 0;
    __syncthreads();
    for (int off = 128; off > 0; off >>= 1) {
        if (tid < off) s[tid] += s[tid + off];
        __syncthreads();
    }
    if (tid == 0) chunkSum[blockIdx.x] = s[0];
}

// single-thread exclusive scan of chunkSum (in place); also rowStart[N_NODES]=N_EDGE
__global__ void lgcn_chunkscan(int* __restrict__ chunkSum, int* __restrict__ rowStart) {
    if (blockIdx.x == 0 && threadIdx.x == 0) {
        int run = 0;
        for (int j = 0; j < NCHUNK; ++j) {
            int t = chunkSum[j];
            chunkSum[j] = run;
            run += t;
        }
        rowStart[N_NODES] = N_EDGE;
    }
}

// per-chunk exclusive scan of cnt + chunkBase -> rowStart, rowNext
__global__ void lgcn_scan(const int* __restrict__ cnt, const int* __restrict__ chunkBase,
                          int* __restrict__ rowStart, int* __restrict__ rowNext) {
    __shared__ int s[256];
    int tid = threadIdx.x;
    int i = blockIdx.x * 256 + tid;
    int v = (i < N_NODES) ? cnt[i] : 0;
    s[tid] = v;
    __syncthreads();
    // Hillis-Steele inclusive scan
    for (int off = 1; off < 256; off <<= 1) {
        int t = (tid >= off) ? s[tid - off] : 0;
        __syncthreads();
        s[tid] += t;
        __syncthreads();
    }
    int excl = s[tid] - v + chunkBase[blockIdx.x];
    if (i < N_NODES) {
        rowStart[i] = excl;
        rowNext[i] = excl;
    }
}

// place edges into CSR order
__global__ void lgcn_place(const int* __restrict__ row, const int* __restrict__ col,
                           const float* __restrict__ vals,
                           int* __restrict__ rowNext,
                           int* __restrict__ colS, unsigned short* __restrict__ valS) {
    int e = blockIdx.x * blockDim.x + threadIdx.x;
    if (e >= N_EDGE) return;
    int r = row[e];
    int pos = atomicAdd(&rowNext[r], 1);
    colS[pos] = col[e];
    valS[pos] = f32_to_bf16(vals[e]);
}

// SpMM: one wave per row; halves of the wave process alternating edges.
// lane&31 owns dim pair (2*l32, 2*l32+1). Fused: out[row] += sum (fp32).
__global__ void lgcn_spmm(const int* __restrict__ rowStart,
                          const int* __restrict__ colS,
                          const unsigned short* __restrict__ valS,
                          const unsigned int* __restrict__ cur,
                          unsigned int* __restrict__ nxt,
                          float* __restrict__ out) {
    int wid = blockIdx.x * (blockDim.x >> 6) + (threadIdx.x >> 6);
    if (wid >= N_NODES) return;
    int lane = threadIdx.x & 63;
    int half = lane >> 5;
    int l32 = lane & 31;
    int s = rowStart[wid];
    int e = rowStart[wid + 1];
    float sx = 0.f, sy = 0.f;
    for (int k = s + half; k < e; k += 2) {
        int c = colS[k];
        float v = __uint_as_float(((unsigned int)valS[k]) << 16);
        unsigned int p = cur[(size_t)c * 32 + l32];
        float lo = __uint_as_float(p << 16);
        float hi = __uint_as_float(p & 0xffff0000u);
        sx += v * lo;
        sy += v * hi;
    }
    sx += __shfl_xor(sx, 32);
    sy += __shfl_xor(sy, 32);
    if (half == 0) {
        size_t base = (size_t)wid * 32 + l32;
        nxt[base] = pack_bf16x2(sx, sy);
        float2* o2 = (float2*)out;
        float2 t = o2[base];
        t.x += sx;
        t.y += sy;
        o2[base] = t;
    }
}

extern "C" void kernel_launch(void* const* d_in, const int* in_sizes, int n_in,
                              void* d_out, int out_size, void* d_ws, size_t ws_size,
                              hipStream_t stream) {
    const float* uEmb = (const float*)d_in[0];
    const float* iEmb = (const float*)d_in[1];
    const int* erow = (const int*)d_in[2];
    const int* ecol = (const int*)d_in[3];
    const float* evals = (const float*)d_in[4];
    float* out = (float*)d_out;

    // workspace layout
    char* p = (char*)d_ws;
    const size_t curBytes = (size_t)N_NODES * 32 * sizeof(unsigned int);  // 38.4 MB
    unsigned int* curA = (unsigned int*)p; p += curBytes;
    unsigned int* curB = (unsigned int*)p; p += curBytes;
    int* colS = (int*)p; p += (size_t)N_EDGE * sizeof(int);               // 38.4 MB
    unsigned short* valS = (unsigned short*)p; p += (size_t)N_EDGE * sizeof(unsigned short); // 19.2 MB
    int* rowStart = (int*)p; p += (size_t)(N_NODES + 1) * sizeof(int);
    int* rowNext = (int*)p; p += (size_t)N_NODES * sizeof(int);
    int* chunkSum = (int*)p; p += (size_t)NCHUNK * sizeof(int);

    const int T = 256;
    const int G_EDGE = (N_EDGE + T - 1) / T;          // 37500
    const int G_SPMM = (N_NODES + 3) / 4;             // 75000 (4 waves/block)

    // init out + curA(bf16)
    lgcn_init<<<2048, T, 0, stream>>>(uEmb, iEmb, out, curA);

    // CSR build (uses rowNext as the count array first)
    hipMemsetAsync(rowNext, 0, (size_t)N_NODES * sizeof(int), stream);
    lgcn_hist<<<G_EDGE, T, 0, stream>>>(erow, rowNext);
    lgcn_chunksum<<<NCHUNK, T, 0, stream>>>(rowNext, chunkSum);
    lgcn_chunkscan<<<1, 64, 0, stream>>>(chunkSum, rowStart);
    lgcn_scan<<<NCHUNK, T, 0, stream>>>(rowNext, chunkSum, rowStart, rowNext);
    lgcn_place<<<G_EDGE, T, 0, stream>>>(erow, ecol, evals, rowNext, colS, valS);

    // 3 GNN layers, fused acc-update
    unsigned int* cur = curA;
    unsigned int* nxt = curB;
    for (int layer = 0; layer < 3; ++layer) {
        lgcn_spmm<<<G_SPMM, T, 0, stream>>>(rowStart, colS, valS, cur, nxt, out);
        unsigned int* t = cur; cur = nxt; nxt = t;
    }
}